// Round 21
// baseline (177.166 us; speedup 1.0000x reference)
//
#include <hip/hip_runtime.h>

typedef float f16v __attribute__((ext_vector_type(16)));
typedef float f4 __attribute__((ext_vector_type(4)));
typedef float f2 __attribute__((ext_vector_type(2)));

// static_for with FRONTEND-constant indices (SSA, no alloca) — see R6 notes.
// NOTE (R20 lesson): inline-asm operands do NOT capture into lambdas — any asm
// referencing function locals must live at FUNCTION SCOPE (macros, not sfor).
template<int I> struct ic { static constexpr int v = I; };
template<int... I> struct iseq {};
template<int N, int... I> struct mk : mk<N-1, N-1, I...> {};
template<int... I> struct mk<0, I...> { using t = iseq<I...>; };
template<class F, int... I>
__device__ __forceinline__ void sfor_impl(F f, iseq<I...>) { (f(ic<I>{}), ...); }
template<int N, class F>
__device__ __forceinline__ void sfor(F f) { sfor_impl(f, typename mk<N>::t{}); }

namespace {
constexpr float kSigma  = 1.2f;    // 2*l2_reg + rho
constexpr float kJitter = 1e-5f;
constexpr int   kIters  = 100;
constexpr int   MD = 16;
constexpr int   ND = 32;
constexpr int   SPA = 4;     // samples per 128-thread block (32 lanes each)
constexpr int   AS  = 132;   // A sample stride in float4
}

__device__ __forceinline__ float4 lds_a4(const float* As, int r, int j) {
    return *reinterpret_cast<const float4*>(&As[r * 32 + ((j ^ (r & 7)) << 2)]);
}
__device__ __forceinline__ float lds_a(const float* As, int r, int n) {
    return As[r * 32 + ((((n >> 2) ^ (r & 7)) << 2) | (n & 3))];
}

// xor lane^16 within each 32-lane group (BitMode: offset = (16<<10)|0x1F = 0x401F)
__device__ __forceinline__ float swz16(float x) {
    return __int_as_float(__builtin_amdgcn_ds_swizzle(__float_as_int(x), 0x401F));
}

// ====== Fused kernel: 32 lanes/sample, 1 P-row/lane (Q=32 regs -> NO AGPR parking) ======
// R19's counters showed the 64-Q-per-lane layout forced ~72 values into AGPRs with
// ~60 v_accvgpr_read per iteration (the 2x instr inflation behind 155us at 97% VALUBusy).
// Here each lane owns ONE row: Q=32 floats, peak live ~70 regs, all-arch.
// Ring: own-half cols via v_fmac_f32_dpp row_ror:j (verified R18/R19); opposite-half
// via ONE ds_swizzle xor16 per operand per iteration.
//   QA_j = P[l][((l-j)&15) + (l&16)]   (own half),   QB_j = P[l][((l-j)&15) + ((l&16)^16)]
// Identity (col==l) lands only in QA_0.
__global__ void __launch_bounds__(128)
admm_fused_kernel(const float* __restrict__ Ag, const float* __restrict__ bg,
                  const float* __restrict__ cg, const float* __restrict__ lbg,
                  const float* __restrict__ ubg, float* __restrict__ outg)
{
    __shared__ __align__(16) float A_lds[SPA * AS * 4];   // 8448 B

    const int t = threadIdx.x;

    // ---- stage A for the block's 4 samples (coalesced, xor-swizzled f4)
    {
        const float4* src = reinterpret_cast<const float4*>(Ag) +
                            (size_t)blockIdx.x * (SPA * MD * ND / 4);
        float4* dst = reinterpret_cast<float4*>(A_lds);
        #pragma unroll
        for (int r = 0; r < 4; ++r) {               // 512 f4 / 128 threads
            int idx = r * 128 + t;
            int smp = idx >> 7;
            int row = (idx >> 3) & 15;
            int j   = idx & 7;
            dst[smp * AS + row * 8 + (j ^ (row & 7))] = src[idx];
        }
    }
    __syncthreads();   // only barrier

    const int lane = t & 63;
    const int l    = lane & 31;                     // P-row / variable owned by this lane
    const int lr   = l & 15;                        // M-row (duplicated in upper half)
    const int smp  = (t >> 6) * 2 + (lane >> 5);
    const size_t gs = (size_t)blockIdx.x * SPA + smp;
    const float* As = &A_lds[smp * AS * 4];

    // ---- A row lr into registers (for M build; dup across halves)
    f16v Ar0, Ar1;
    sfor<4>([&](auto J) {
        constexpr int j = decltype(J)::v;
        float4 v  = lds_a4(As, lr, j);
        Ar0[4*j+0] = v.x;  Ar0[4*j+1] = v.y;  Ar0[4*j+2] = v.z;  Ar0[4*j+3] = v.w;
        float4 w4 = lds_a4(As, lr, j + 4);
        Ar1[4*j+0] = w4.x; Ar1[4*j+1] = w4.y; Ar1[4*j+2] = w4.z; Ar1[4*j+3] = w4.w;
    });

    // ---- M = A A^T + jitter*I (row lr)
    f16v Mrow, Vrow;
    sfor<16>([&](auto K) {
        constexpr int k = decltype(K)::v;
        float a0 = 0.f, a1 = 0.f, a2 = 0.f, a3 = 0.f;
        sfor<4>([&](auto J) {
            constexpr int j = decltype(J)::v;
            float4 v  = lds_a4(As, k, j);
            a0 += Ar0[4*j+0]*v.x;  a1 += Ar0[4*j+1]*v.y;
            a2 += Ar0[4*j+2]*v.z;  a3 += Ar0[4*j+3]*v.w;
            float4 w4 = lds_a4(As, k, j + 4);
            a0 += Ar1[4*j+0]*w4.x; a1 += Ar1[4*j+1]*w4.y;
            a2 += Ar1[4*j+2]*w4.z; a3 += Ar1[4*j+3]*w4.w;
        });
        Mrow[k] = (a0+a1)+(a2+a3) + ((k == lr) ? kJitter : 0.f);
        Vrow[k] = (k == lr) ? 1.f : 0.f;
    });

    // ---- triangular Gauss-Jordan (SPD), width-32 shuffles, lr-duplicated (R8-proven)
    sfor<16>([&](auto K) {
        constexpr int k = decltype(K)::v;
        float ip = 1.f / __shfl(Mrow[k], k, 32);
        float f  = (lr == k) ? 0.f : Mrow[k] * ip;
        sfor<16>([&](auto J) {
            constexpr int j = decltype(J)::v;
            if constexpr (j > k) {
                float mj = __shfl(Mrow[j], k, 32);
                Mrow[j] = (lr == k) ? mj * ip : Mrow[j] - f * mj;
            }
        });
        sfor<16>([&](auto J) {
            constexpr int j = decltype(J)::v;
            if constexpr (j < k) {
                float vj = __shfl(Vrow[j], k, 32);
                Vrow[j] = (lr == k) ? vj * ip : Vrow[j] - f * vj;
            }
        });
        Vrow[k] = (lr == k) ? ip : -f;
    });

    // ---- w = Minv b (lane holds w[lr], dup)
    float w = 0.f;
    {
        float bval = bg[gs * MD + lr];
        sfor<16>([&](auto K) {
            constexpr int k = decltype(K)::v;
            w += Vrow[k] * __shfl(bval, k, 32);
        });
    }

    // ---- C row l of A^T Minv (16 floats) + q = (A^T w)[l]
    f16v C = (f16v)0.0f;
    float q = 0.f;
    sfor<16>([&](auto K) {
        constexpr int k = decltype(K)::v;
        float a = lds_a(As, k, l);
        q = fmaf(a, __shfl(w, k, 32), q);
        sfor<16>([&](auto M) {
            constexpr int m = decltype(M)::v;
            C[m] = fmaf(a, __shfl(Vrow[m], k, 32), C[m]);
        });
    });

    // ---- Q ring-build (rolling DPP) at FUNCTION SCOPE (asm can't live in lambdas).
    // Per row m: read A[m][l], A[m][l^16] once; fmac_dpp ror:j spreads to all slots.
    float QA0=0,QA1=0,QA2=0,QA3=0,QA4=0,QA5=0,QA6=0,QA7=0,
          QA8=0,QA9=0,QA10=0,QA11=0,QA12=0,QA13=0,QA14=0,QA15=0;
    float QB0=0,QB1=0,QB2=0,QB3=0,QB4=0,QB5=0,QB6=0,QB7=0,
          QB8=0,QB9=0,QB10=0,QB11=0,QB12=0,QB13=0,QB14=0,QB15=0;
#define QROLL(ACC, SRC, CM, J)                                                \
    asm("v_fmac_f32_dpp %0, %1, %2 row_ror:" #J " row_mask:0xf bank_mask:0xf" \
        : "+v"(ACC) : "v"(SRC), "v"(CM));
#define QROW(m) {                                                             \
        float ako = lds_a(As, (m), l);        /* A[m][l]    */                \
        float ake = lds_a(As, (m), l ^ 16);   /* A[m][l^16] */                \
        float cm  = C[m];                                                     \
        QA0 = fmaf(ako, cm, QA0);                                             \
        QROLL(QA1, ako, cm, 1)  QROLL(QA2, ako, cm, 2)  QROLL(QA3, ako, cm, 3)\
        QROLL(QA4, ako, cm, 4)  QROLL(QA5, ako, cm, 5)  QROLL(QA6, ako, cm, 6)\
        QROLL(QA7, ako, cm, 7)  QROLL(QA8, ako, cm, 8)  QROLL(QA9, ako, cm, 9)\
        QROLL(QA10, ako, cm, 10) QROLL(QA11, ako, cm, 11)                     \
        QROLL(QA12, ako, cm, 12) QROLL(QA13, ako, cm, 13)                     \
        QROLL(QA14, ako, cm, 14) QROLL(QA15, ako, cm, 15)                     \
        QB0 = fmaf(ake, cm, QB0);                                             \
        QROLL(QB1, ake, cm, 1)  QROLL(QB2, ake, cm, 2)  QROLL(QB3, ake, cm, 3)\
        QROLL(QB4, ake, cm, 4)  QROLL(QB5, ake, cm, 5)  QROLL(QB6, ake, cm, 6)\
        QROLL(QB7, ake, cm, 7)  QROLL(QB8, ake, cm, 8)  QROLL(QB9, ake, cm, 9)\
        QROLL(QB10, ake, cm, 10) QROLL(QB11, ake, cm, 11)                     \
        QROLL(QB12, ake, cm, 12) QROLL(QB13, ake, cm, 13)                     \
        QROLL(QB14, ake, cm, 14) QROLL(QB15, ake, cm, 15)                     \
    }
    QROW(0)  QROW(1)  QROW(2)  QROW(3)
    QROW(4)  QROW(5)  QROW(6)  QROW(7)
    QROW(8)  QROW(9)  QROW(10) QROW(11)
    QROW(12) QROW(13) QROW(14) QROW(15)
#undef QROW
#undef QROLL
    // finalize: Q = (I - CA)/sigma; identity only in QA_0
    constexpr float is = 1.f / kSigma;
    QA0 = (1.f - QA0) * is;
#define QFIN(X) X = -X * is;
    QFIN(QA1) QFIN(QA2) QFIN(QA3) QFIN(QA4) QFIN(QA5) QFIN(QA6) QFIN(QA7)
    QFIN(QA8) QFIN(QA9) QFIN(QA10) QFIN(QA11) QFIN(QA12) QFIN(QA13) QFIN(QA14) QFIN(QA15)
    QFIN(QB0) QFIN(QB1) QFIN(QB2) QFIN(QB3) QFIN(QB4) QFIN(QB5) QFIN(QB6) QFIN(QB7)
    QFIN(QB8) QFIN(QB9) QFIN(QB10) QFIN(QB11) QFIN(QB12) QFIN(QB13) QFIN(QB14) QFIN(QB15)
#undef QFIN

    // ---- d = q - P c (same ring on c)
    float d;
    {
        float cown = cg[gs * ND + l];
        float copp = swz16(cown);
        float pA = QA0 * cown, pB = QB0 * copp;
#define DROLL(ACC, SRC, QJ, J)                                                \
        asm("v_fmac_f32_dpp %0, %1, %2 row_ror:" #J " row_mask:0xf bank_mask:0xf" \
            : "+v"(ACC) : "v"(SRC), "v"(QJ));
        DROLL(pA, cown, QA1, 1)  DROLL(pA, cown, QA2, 2)  DROLL(pA, cown, QA3, 3)
        DROLL(pA, cown, QA4, 4)  DROLL(pA, cown, QA5, 5)  DROLL(pA, cown, QA6, 6)
        DROLL(pA, cown, QA7, 7)  DROLL(pA, cown, QA8, 8)  DROLL(pA, cown, QA9, 9)
        DROLL(pA, cown, QA10, 10) DROLL(pA, cown, QA11, 11) DROLL(pA, cown, QA12, 12)
        DROLL(pA, cown, QA13, 13) DROLL(pA, cown, QA14, 14) DROLL(pA, cown, QA15, 15)
        DROLL(pB, copp, QB1, 1)  DROLL(pB, copp, QB2, 2)  DROLL(pB, copp, QB3, 3)
        DROLL(pB, copp, QB4, 4)  DROLL(pB, copp, QB5, 5)  DROLL(pB, copp, QB6, 6)
        DROLL(pB, copp, QB7, 7)  DROLL(pB, copp, QB8, 8)  DROLL(pB, copp, QB9, 9)
        DROLL(pB, copp, QB10, 10) DROLL(pB, copp, QB11, 11) DROLL(pB, copp, QB12, 12)
        DROLL(pB, copp, QB13, 13) DROLL(pB, copp, QB14, 14) DROLL(pB, copp, QB15, 15)
#undef DROLL
        d = q - (pA + pB);
    }

    // ================= Phase 2: 100 iterations =================
    float lb = lbg[gs * ND + l];
    float ub = ubg[gs * ND + l];
    float z  = fminf(fmaxf(0.f, lb), ub);
    float u  = 0.f, x = 0.f;

#define FSTEP(ACC, SRC, QJ, J)                                                \
    asm("v_fmac_f32_dpp %0, %1, %2 row_ror:" #J " row_mask:0xf bank_mask:0xf" \
        : "+v"(ACC) : "v"(SRC), "v"(QJ));
    for (int it = 0; it < kIters; ++it) {
        float s   = z - u;                 // own variable's s (rho == 1)
        float sop = swz16(s);              // opposite half's s (1 DS op)
        // 4 chains, 8 deep each
        float a0 = fmaf(QA0, s, d);
        float a1 = 0.f;
        float b0 = QB0 * sop;
        float b1 = 0.f;
        FSTEP(a0, s, QA1, 1)  FSTEP(a0, s, QA2, 2)  FSTEP(a0, s, QA3, 3)
        FSTEP(a0, s, QA4, 4)  FSTEP(a0, s, QA5, 5)  FSTEP(a0, s, QA6, 6)
        FSTEP(a0, s, QA7, 7)
        FSTEP(a1, s, QA8, 8)  FSTEP(a1, s, QA9, 9)  FSTEP(a1, s, QA10, 10)
        FSTEP(a1, s, QA11, 11) FSTEP(a1, s, QA12, 12) FSTEP(a1, s, QA13, 13)
        FSTEP(a1, s, QA14, 14) FSTEP(a1, s, QA15, 15)
        FSTEP(b0, sop, QB1, 1)  FSTEP(b0, sop, QB2, 2)  FSTEP(b0, sop, QB3, 3)
        FSTEP(b0, sop, QB4, 4)  FSTEP(b0, sop, QB5, 5)  FSTEP(b0, sop, QB6, 6)
        FSTEP(b0, sop, QB7, 7)
        FSTEP(b1, sop, QB8, 8)  FSTEP(b1, sop, QB9, 9)  FSTEP(b1, sop, QB10, 10)
        FSTEP(b1, sop, QB11, 11) FSTEP(b1, sop, QB12, 12) FSTEP(b1, sop, QB13, 13)
        FSTEP(b1, sop, QB14, 14) FSTEP(b1, sop, QB15, 15)
        x = (a0 + a1) + (b0 + b1);
        float tv = x + u;
        z = fminf(fmaxf(tv, lb), ub);
        u = tv - z;
    }
#undef FSTEP

    outg[gs * ND + l] = x;
}

extern "C" void kernel_launch(void* const* d_in, const int* in_sizes, int n_in,
                              void* d_out, int out_size, void* d_ws, size_t ws_size,
                              hipStream_t stream) {
    const float* A  = (const float*)d_in[0];
    const float* b  = (const float*)d_in[1];
    const float* c  = (const float*)d_in[2];
    const float* lb = (const float*)d_in[3];
    const float* ub = (const float*)d_in[4];
    float* out = (float*)d_out;
    const int B = in_sizes[1] / MD;      // 32768 samples
    admm_fused_kernel<<<B / SPA, 128, 0, stream>>>(A, b, c, lb, ub, out);
}